// Round 4
// baseline (56.583 us; speedup 1.0000x reference)
//
#include <hip/hip_runtime.h>

#define VOCAB 100000
#define D 300
#define NS 256
#define NA 256
#define W 8
#define NROWS 2048   // 256*8
#define KP 304       // D padded to multiple of 16
#define BK 16
#define NSTAGE (KP / BK)   // 19
#define FR 12              // fragment slot stride (floats): 8 data + 4 pad
#define KROW 196           // k-plane stride (floats): 16*FR + 4 (bank rotate)

// ---------------- gather + reciprocal norms + none flags ----------------
__global__ __launch_bounds__(64) void k_gather(const float* __restrict__ emb,
                                               const int* __restrict__ sen_cats,
                                               const int* __restrict__ ann_cats,
                                               const int* __restrict__ none_idx,
                                               float* __restrict__ Arow,
                                               float* __restrict__ Brow,
                                               float* __restrict__ rsn,
                                               float* __restrict__ ran,
                                               int* __restrict__ sflag) {
    int rid = blockIdx.x;
    bool isSen = rid < NROWS;
    int r = isSen ? rid : rid - NROWS;
    int cat = isSen ? sen_cats[r] : ann_cats[r];
    const float4* src = reinterpret_cast<const float4*>(emb + (size_t)cat * D);
    float4* dst = reinterpret_cast<float4*>((isSen ? Arow : Brow) + (size_t)r * KP);
    int tid = threadIdx.x;
    double acc = 0.0;
    for (int i = tid; i < 75; i += 64) {        // 300 floats = 75 float4
        float4 v = src[i];
        dst[i] = v;
        acc += (double)v.x * v.x + (double)v.y * v.y +
               (double)v.z * v.z + (double)v.w * v.w;
    }
    if (tid == 0) dst[75] = make_float4(0.f, 0.f, 0.f, 0.f);  // zero K-pad
    for (int off = 32; off > 0; off >>= 1) acc += __shfl_down(acc, off, 64);
    if (tid == 0) {
        float rn = (float)(1.0 / sqrt(acc));   // norms ~17, eps clamp unreachable
        if (isSen) {
            rsn[r] = rn;
            sflag[r] = (cat == none_idx[0]) ? 1 : 0;
        } else {
            ran[r] = rn;
        }
    }
}

// ---------------- sen_wd_emb = sum over w of sen_e ----------------
__global__ __launch_bounds__(128) void k_sumemb(const float* __restrict__ Arow,
                                                float* __restrict__ out2) {
    int s = blockIdx.x;
    for (int d = threadIdx.x; d < D; d += 128) {
        float sum = 0.f;
#pragma unroll
        for (int w = 0; w < W; ++w)
            sum += Arow[(size_t)(s * W + w) * KP + d];
        out2[s * D + d] = sum;
    }
}

// ---------------- main: fp32, bank-spread fragment LDS, dbuf, in-reg fold ----
__global__ __launch_bounds__(256, 1) void k_main(const float* __restrict__ Arow,
                                                 const float* __restrict__ Brow,
                                                 const float* __restrict__ rsn,
                                                 const float* __restrict__ ran,
                                                 const int* __restrict__ sflag,
                                                 float* __restrict__ out) {
    // layout: As[buf][k][frag f at offset f*FR, elems 0..7]; KROW rotates banks
    __shared__ float As[2][BK][KROW];
    __shared__ float Bs[2][BK][KROW];

    int tid = threadIdx.x;
    int wv = tid >> 6, lane = tid & 63;
    int qy = wv >> 1, qx = wv & 1;          // wave's 64x64 quadrant
    int ty8 = lane >> 3, tx8 = lane & 7;    // 8x8 lane grid inside quadrant
    int aOff = qy * (8 * FR) + ty8 * FR;    // fragment base (floats) in a k-plane
    int bOff = qx * (8 * FR) + tx8 * FR;
    int by = blockIdx.y, bx = blockIdx.x;

    // staging map: q = k-quad (0..3), r0 = tile row (0..63); rows r0, r0+64
    int q = tid & 3, r0 = tid >> 2;
    int kb = q * 4;
    int frag0 = (r0 >> 3) * FR + (r0 & 7);  // LDS slot of row r0
    int frag1 = frag0 + 8 * FR;             // row r0+64
    const float* Ag = Arow + (size_t)(by * 128 + r0) * KP + q * 4;
    const float* Bg = Brow + (size_t)(bx * 128 + r0) * KP + q * 4;

    // prologue: stage 0 into buffer 0
    float4 pa0 = *reinterpret_cast<const float4*>(Ag);
    float4 pa1 = *reinterpret_cast<const float4*>(Ag + 64 * KP);
    float4 pb0 = *reinterpret_cast<const float4*>(Bg);
    float4 pb1 = *reinterpret_cast<const float4*>(Bg + 64 * KP);
    {
        float av0[4] = {pa0.x, pa0.y, pa0.z, pa0.w};
        float av1[4] = {pa1.x, pa1.y, pa1.z, pa1.w};
        float bv0[4] = {pb0.x, pb0.y, pb0.z, pb0.w};
        float bv1[4] = {pb1.x, pb1.y, pb1.z, pb1.w};
#pragma unroll
        for (int i = 0; i < 4; ++i) {
            As[0][kb + i][frag0] = av0[i];
            As[0][kb + i][frag1] = av1[i];
            Bs[0][kb + i][frag0] = bv0[i];
            Bs[0][kb + i][frag1] = bv1[i];
        }
    }

    float acc[W][W] = {};

    for (int st = 0; st < NSTAGE; ++st) {
        int cur = st & 1;
        __syncthreads();   // stage st's LDS writes visible; prev reads done
        // issue next-stage global loads (latency hidden under compute)
        if (st + 1 < NSTAGE) {
            const float* Ag2 = Ag + (st + 1) * BK;
            const float* Bg2 = Bg + (st + 1) * BK;
            pa0 = *reinterpret_cast<const float4*>(Ag2);
            pa1 = *reinterpret_cast<const float4*>(Ag2 + 64 * KP);
            pb0 = *reinterpret_cast<const float4*>(Bg2);
            pb1 = *reinterpret_cast<const float4*>(Bg2 + 64 * KP);
        }
#pragma unroll
        for (int kk = 0; kk < BK; ++kk) {
            float4 a0 = *reinterpret_cast<const float4*>(&As[cur][kk][aOff]);
            float4 a1 = *reinterpret_cast<const float4*>(&As[cur][kk][aOff + 4]);
            float4 b0 = *reinterpret_cast<const float4*>(&Bs[cur][kk][bOff]);
            float4 b1 = *reinterpret_cast<const float4*>(&Bs[cur][kk][bOff + 4]);
            float av[W] = {a0.x, a0.y, a0.z, a0.w, a1.x, a1.y, a1.z, a1.w};
            float bv[W] = {b0.x, b0.y, b0.z, b0.w, b1.x, b1.y, b1.z, b1.w};
#pragma unroll
            for (int w = 0; w < W; ++w)
#pragma unroll
                for (int v = 0; v < W; ++v)
                    acc[w][v] = __builtin_fmaf(av[w], bv[v], acc[w][v]);
        }
        // write stage st+1 into the other buffer (overlaps compute via scheduler)
        if (st + 1 < NSTAGE) {
            int nxt = cur ^ 1;
            float av0[4] = {pa0.x, pa0.y, pa0.z, pa0.w};
            float av1[4] = {pa1.x, pa1.y, pa1.z, pa1.w};
            float bv0[4] = {pb0.x, pb0.y, pb0.z, pb0.w};
            float bv1[4] = {pb1.x, pb1.y, pb1.z, pb1.w};
#pragma unroll
            for (int i = 0; i < 4; ++i) {
                As[nxt][kb + i][frag0] = av0[i];
                As[nxt][kb + i][frag1] = av1[i];
                Bs[nxt][kb + i][frag0] = bv0[i];
                Bs[nxt][kb + i][frag1] = bv1[i];
            }
        }
    }

    // epilogue: cosine + order-dependent fold, all in registers (fp32)
    int s = by * 16 + qy * 8 + ty8;
    int a = bx * 16 + qx * 8 + tx8;
    float rs[W], ra[W];
    int fl[W];
#pragma unroll
    for (int w = 0; w < W; ++w) {
        rs[w] = rsn[s * W + w];
        fl[w] = sflag[s * W + w];
    }
#pragma unroll
    for (int v = 0; v < W; ++v) ra[v] = ran[a * W + v];

    float cur = 0.f;
#pragma unroll
    for (int w = 0; w < W; ++w) {
        float rw = rs[w];
        int f = fl[w];
#pragma unroll
        for (int v = 0; v < W; ++v) {
            float cv = f ? 0.f : acc[w][v] * (rw * ra[v]);
            cur = (cv >= cur || cv < 0.f) ? cv : cur;
        }
    }
    out[s * NA + a] = cur;
}

extern "C" void kernel_launch(void* const* d_in, const int* in_sizes, int n_in,
                              void* d_out, int out_size, void* d_ws, size_t ws_size,
                              hipStream_t stream) {
    const float* emb = (const float*)d_in[0];
    const int* sen = (const int*)d_in[1];
    const int* ann = (const int*)d_in[2];
    const int* none = (const int*)d_in[3];
    float* out = (float*)d_out;

    char* ws = (char*)d_ws;
    float* Arow = (float*)(ws + 0);                  // 2048*304*4 = 2,490,368
    float* Brow = (float*)(ws + 2490368);            // 2,490,368
    float* rsn = (float*)(ws + 4980736);             // 8,192
    float* ran = (float*)(ws + 4988928);             // 8,192
    int* sflag = (int*)(ws + 4997120);               // 8,192

    hipLaunchKernelGGL(k_gather, dim3(4096), dim3(64), 0, stream,
                       emb, sen, ann, none, Arow, Brow, rsn, ran, sflag);
    hipLaunchKernelGGL(k_sumemb, dim3(256), dim3(128), 0, stream,
                       Arow, out + NS * NA);
    hipLaunchKernelGGL(k_main, dim3(16, 16), dim3(256), 0, stream,
                       Arow, Brow, rsn, ran, sflag, out);
}

// Round 5
// 51.165 us; speedup vs baseline: 1.1059x; 1.1059x over previous
//
#include <hip/hip_runtime.h>

#define D 300
#define NS 256
#define NA 256
#define W 8
#define NROWS 2048   // 256*8
#define KP 304       // D padded to multiple of 16
#define BK 16
#define NSTAGE (KP / BK)   // 19
#define FR 12              // fragment slot stride (floats): 8 data + 4 pad
#define KROW 196           // k-plane stride (floats): 16*FR + 4 (bank rotate)

// ------- gather + reciprocal norms + none flags + sen_wd_emb (merged) -------
__global__ __launch_bounds__(64) void k_gather(const float* __restrict__ emb,
                                               const int* __restrict__ sen_cats,
                                               const int* __restrict__ ann_cats,
                                               const int* __restrict__ none_idx,
                                               float* __restrict__ Arow,
                                               float* __restrict__ Brow,
                                               float* __restrict__ rsn,
                                               float* __restrict__ ran,
                                               int* __restrict__ sflag,
                                               float* __restrict__ out2) {
    int b = blockIdx.x, tid = threadIdx.x;
    if (b < NS) {
        // sen category b: 8 rows; also accumulate the word-sum -> out2
        bool has2 = (tid + 64) < 75;            // 75 float4 per row
        float4 sum0 = make_float4(0.f, 0.f, 0.f, 0.f);
        float4 sum1 = make_float4(0.f, 0.f, 0.f, 0.f);
        int nidx = none_idx[0];
        for (int w = 0; w < W; ++w) {
            int r = b * W + w;
            int cat = sen_cats[r];
            const float4* src = reinterpret_cast<const float4*>(emb + (size_t)cat * D);
            float4* dst = reinterpret_cast<float4*>(Arow + (size_t)r * KP);
            float4 v0 = src[tid];
            dst[tid] = v0;
            double acc = (double)v0.x * v0.x + (double)v0.y * v0.y +
                         (double)v0.z * v0.z + (double)v0.w * v0.w;
            sum0.x += v0.x; sum0.y += v0.y; sum0.z += v0.z; sum0.w += v0.w;
            if (has2) {
                float4 v1 = src[tid + 64];
                dst[tid + 64] = v1;
                acc += (double)v1.x * v1.x + (double)v1.y * v1.y +
                       (double)v1.z * v1.z + (double)v1.w * v1.w;
                sum1.x += v1.x; sum1.y += v1.y; sum1.z += v1.z; sum1.w += v1.w;
            }
            if (tid == 0) dst[75] = make_float4(0.f, 0.f, 0.f, 0.f);  // K-pad
            for (int off = 32; off > 0; off >>= 1) acc += __shfl_down(acc, off, 64);
            if (tid == 0) {
                rsn[r] = (float)(1.0 / sqrt(acc));  // norms ~17, eps unreachable
                sflag[r] = (cat == nidx) ? 1 : 0;
            }
        }
        float4* o = reinterpret_cast<float4*>(out2 + (size_t)b * D);  // 1200B rows, 16B aligned
        o[tid] = sum0;
        if (has2) o[tid + 64] = sum1;
    } else {
        // ann row (one per block)
        int r = b - NS;
        int cat = ann_cats[r];
        const float4* src = reinterpret_cast<const float4*>(emb + (size_t)cat * D);
        float4* dst = reinterpret_cast<float4*>(Brow + (size_t)r * KP);
        double acc = 0.0;
        for (int i = tid; i < 75; i += 64) {
            float4 v = src[i];
            dst[i] = v;
            acc += (double)v.x * v.x + (double)v.y * v.y +
                   (double)v.z * v.z + (double)v.w * v.w;
        }
        if (tid == 0) dst[75] = make_float4(0.f, 0.f, 0.f, 0.f);
        for (int off = 32; off > 0; off >>= 1) acc += __shfl_down(acc, off, 64);
        if (tid == 0) ran[r] = (float)(1.0 / sqrt(acc));
    }
}

// --- main: fp32, explicit 1-deep register pipeline over kk, dbuf LDS, in-reg fold ---
__global__ __launch_bounds__(256, 1) void k_main(const float* __restrict__ Arow,
                                                 const float* __restrict__ Brow,
                                                 const float* __restrict__ rsn,
                                                 const float* __restrict__ ran,
                                                 const int* __restrict__ sflag,
                                                 float* __restrict__ out) {
    __shared__ float As[2][BK][KROW];
    __shared__ float Bs[2][BK][KROW];

    int tid = threadIdx.x;
    int wv = tid >> 6, lane = tid & 63;
    int qy = wv >> 1, qx = wv & 1;          // wave's 64x64 quadrant
    int ty8 = lane >> 3, tx8 = lane & 7;    // 8x8 lane grid inside quadrant
    int aOff = qy * (8 * FR) + ty8 * FR;    // fragment base (floats) in a k-plane
    int bOff = qx * (8 * FR) + tx8 * FR;
    int by = blockIdx.y, bx = blockIdx.x;

    // staging map: q = k-quad (0..3), r0 = tile row (0..63); rows r0, r0+64
    int q = tid & 3, r0 = tid >> 2;
    int kb = q * 4;
    int frag0 = (r0 >> 3) * FR + (r0 & 7);  // LDS slot of row r0
    int frag1 = frag0 + 8 * FR;             // row r0+64
    const float* Ag = Arow + (size_t)(by * 128 + r0) * KP + q * 4;
    const float* Bg = Brow + (size_t)(bx * 128 + r0) * KP + q * 4;

    // prologue: stage 0 into buffer 0
    float4 pa0 = *reinterpret_cast<const float4*>(Ag);
    float4 pa1 = *reinterpret_cast<const float4*>(Ag + 64 * KP);
    float4 pb0 = *reinterpret_cast<const float4*>(Bg);
    float4 pb1 = *reinterpret_cast<const float4*>(Bg + 64 * KP);
    {
        float av0[4] = {pa0.x, pa0.y, pa0.z, pa0.w};
        float av1[4] = {pa1.x, pa1.y, pa1.z, pa1.w};
        float bv0[4] = {pb0.x, pb0.y, pb0.z, pb0.w};
        float bv1[4] = {pb1.x, pb1.y, pb1.z, pb1.w};
#pragma unroll
        for (int i = 0; i < 4; ++i) {
            As[0][kb + i][frag0] = av0[i];
            As[0][kb + i][frag1] = av1[i];
            Bs[0][kb + i][frag0] = bv0[i];
            Bs[0][kb + i][frag1] = bv1[i];
        }
    }

    float acc[W][W] = {};

    for (int st = 0; st < NSTAGE; ++st) {
        int cur = st & 1;
        __syncthreads();   // stage st's LDS writes visible; prev reads done
        const float* Abase = &As[cur][0][0];
        const float* Bbase = &Bs[cur][0][0];
        // kk=0 fragment reads issued first (needed immediately)
        float4 ca0 = *reinterpret_cast<const float4*>(Abase + aOff);
        float4 ca1 = *reinterpret_cast<const float4*>(Abase + aOff + 4);
        float4 cb0 = *reinterpret_cast<const float4*>(Bbase + bOff);
        float4 cb1 = *reinterpret_cast<const float4*>(Bbase + bOff + 4);
        // next-stage global loads (needed only at stage end)
        if (st + 1 < NSTAGE) {
            const float* Ag2 = Ag + (st + 1) * BK;
            const float* Bg2 = Bg + (st + 1) * BK;
            pa0 = *reinterpret_cast<const float4*>(Ag2);
            pa1 = *reinterpret_cast<const float4*>(Ag2 + 64 * KP);
            pb0 = *reinterpret_cast<const float4*>(Bg2);
            pb1 = *reinterpret_cast<const float4*>(Bg2 + 64 * KP);
        }
#pragma unroll
        for (int kk = 0; kk < BK; ++kk) {
            float4 na0, na1, nb0, nb1;
            if (kk + 1 < BK) {   // issue kk+1 reads BEFORE kk's FMAs (latency hide)
                const float* An = Abase + (kk + 1) * KROW;
                const float* Bn = Bbase + (kk + 1) * KROW;
                na0 = *reinterpret_cast<const float4*>(An + aOff);
                na1 = *reinterpret_cast<const float4*>(An + aOff + 4);
                nb0 = *reinterpret_cast<const float4*>(Bn + bOff);
                nb1 = *reinterpret_cast<const float4*>(Bn + bOff + 4);
            }
            float av[W] = {ca0.x, ca0.y, ca0.z, ca0.w, ca1.x, ca1.y, ca1.z, ca1.w};
            float bv[W] = {cb0.x, cb0.y, cb0.z, cb0.w, cb1.x, cb1.y, cb1.z, cb1.w};
#pragma unroll
            for (int w = 0; w < W; ++w)
#pragma unroll
                for (int v = 0; v < W; ++v)
                    acc[w][v] = __builtin_fmaf(av[w], bv[v], acc[w][v]);
            if (kk + 1 < BK) {
                ca0 = na0; ca1 = na1; cb0 = nb0; cb1 = nb1;
            }
        }
        // write stage st+1 into the other buffer
        if (st + 1 < NSTAGE) {
            int nxt = cur ^ 1;
            float av0[4] = {pa0.x, pa0.y, pa0.z, pa0.w};
            float av1[4] = {pa1.x, pa1.y, pa1.z, pa1.w};
            float bv0[4] = {pb0.x, pb0.y, pb0.z, pb0.w};
            float bv1[4] = {pb1.x, pb1.y, pb1.z, pb1.w};
#pragma unroll
            for (int i = 0; i < 4; ++i) {
                As[nxt][kb + i][frag0] = av0[i];
                As[nxt][kb + i][frag1] = av1[i];
                Bs[nxt][kb + i][frag0] = bv0[i];
                Bs[nxt][kb + i][frag1] = bv1[i];
            }
        }
    }

    // epilogue: cosine + order-dependent fold, all in registers (fp32)
    int s = by * 16 + qy * 8 + ty8;
    int a = bx * 16 + qx * 8 + tx8;
    float rs[W], ra[W];
    int fl[W];
#pragma unroll
    for (int w = 0; w < W; ++w) {
        rs[w] = rsn[s * W + w];
        fl[w] = sflag[s * W + w];
    }
#pragma unroll
    for (int v = 0; v < W; ++v) ra[v] = ran[a * W + v];

    float cur = 0.f;
#pragma unroll
    for (int w = 0; w < W; ++w) {
        float rw = rs[w];
        int f = fl[w];
#pragma unroll
        for (int v = 0; v < W; ++v) {
            float cv = f ? 0.f : acc[w][v] * (rw * ra[v]);
            cur = (cv >= cur || cv < 0.f) ? cv : cur;
        }
    }
    out[s * NA + a] = cur;
}

extern "C" void kernel_launch(void* const* d_in, const int* in_sizes, int n_in,
                              void* d_out, int out_size, void* d_ws, size_t ws_size,
                              hipStream_t stream) {
    const float* emb = (const float*)d_in[0];
    const int* sen = (const int*)d_in[1];
    const int* ann = (const int*)d_in[2];
    const int* none = (const int*)d_in[3];
    float* out = (float*)d_out;

    char* ws = (char*)d_ws;
    float* Arow = (float*)(ws + 0);                  // 2048*304*4 = 2,490,368
    float* Brow = (float*)(ws + 2490368);            // 2,490,368
    float* rsn = (float*)(ws + 4980736);             // 8,192
    float* ran = (float*)(ws + 4988928);             // 8,192
    int* sflag = (int*)(ws + 4997120);               // 8,192

    hipLaunchKernelGGL(k_gather, dim3(NS + NROWS), dim3(64), 0, stream,
                       emb, sen, ann, none, Arow, Brow, rsn, ran, sflag,
                       out + NS * NA);
    hipLaunchKernelGGL(k_main, dim3(16, 16), dim3(256), 0, stream,
                       Arow, Brow, rsn, ran, sflag, out);
}